// Round 4
// baseline (278.336 us; speedup 1.0000x reference)
//
#include <hip/hip_runtime.h>

namespace {

constexpr int NB = 4;
constexpr int ND = 128;
constexpr int NH = 192;
constexpr int NW = 192;
constexpr int CD = 16;   // output planes per block; 128/16 = 8 exact

__global__ __launch_bounds__(256, 6)
void edge_loss3d(const float* __restrict__ pred,
                 const float* __restrict__ targ,
                 float* __restrict__ out)
{
    const int lane = threadIdx.x & 63;
    const int wid  = threadIdx.x >> 6;
    const int d0   = blockIdx.x * CD;
    const int h    = blockIdx.y * 4 + wid;   // output row, 0..191
    const int b    = blockIdx.z;
    const int w0   = lane * 3;               // 64 lanes x 3 w = 192, all active

    const long long PL = (long long)NH * NW;
    const float* pb0 = pred + (long long)b * ND * PL + w0;
    const float* pb1 = targ + (long long)b * ND * PL + w0;

    // per-wave h-row offsets (clamped) and validity masks
    const int ho0 = (h - 1 < 0 ? 0 : h - 1) * NW;
    const int ho1 = h * NW;
    const int ho2 = (h + 1 > NH - 1 ? NH - 1 : h + 1) * NW;
    const float hm0 = (h - 1 >= 0) ? 1.f : 0.f;
    const float hm2 = (h + 1 < NH) ? 1.f : 0.f;

    // rolling state: q[tensor][slot][kind 0=ss 1=ts 2=st][w] — literal indices only
    float q[2][3][3][3];
    float acc = 0.f;

#define MATHROW(T, SP, RR, X0, X1, X2) do {                                   \
    float xl_ = __shfl_up((X2), 1, 64);   if (lane == 0)  xl_ = 0.f;          \
    float xr_ = __shfl_down((X0), 1, 64); if (lane == 63) xr_ = 0.f;          \
    const float s0_ = fmaf(2.f, (X0), xl_ + (X1)) * 0.25f;                    \
    const float s1_ = fmaf(2.f, (X1), (X0) + (X2)) * 0.25f;                   \
    const float s2_ = fmaf(2.f, (X2), (X1) + xr_) * 0.25f;                    \
    const float t0_ = (X1) - xl_, t1_ = (X2) - (X0), t2_ = xr_ - (X1);        \
    if ((RR) == 0) {                                                          \
        q[T][SP][0][0] = 0.25f*s0_; q[T][SP][0][1] = 0.25f*s1_; q[T][SP][0][2] = 0.25f*s2_; \
        q[T][SP][1][0] = -s0_;      q[T][SP][1][1] = -s1_;      q[T][SP][1][2] = -s2_;      \
        q[T][SP][2][0] = 0.25f*t0_; q[T][SP][2][1] = 0.25f*t1_; q[T][SP][2][2] = 0.25f*t2_; \
    } else if ((RR) == 1) {                                                   \
        q[T][SP][0][0] = fmaf(0.5f, s0_, q[T][SP][0][0]);                     \
        q[T][SP][0][1] = fmaf(0.5f, s1_, q[T][SP][0][1]);                     \
        q[T][SP][0][2] = fmaf(0.5f, s2_, q[T][SP][0][2]);                     \
        /* sobel_h center weight = 0 -> ts unchanged */                       \
        q[T][SP][2][0] = fmaf(0.5f, t0_, q[T][SP][2][0]);                     \
        q[T][SP][2][1] = fmaf(0.5f, t1_, q[T][SP][2][1]);                     \
        q[T][SP][2][2] = fmaf(0.5f, t2_, q[T][SP][2][2]);                     \
    } else {                                                                  \
        q[T][SP][0][0] = fmaf(0.25f, s0_, q[T][SP][0][0]);                    \
        q[T][SP][0][1] = fmaf(0.25f, s1_, q[T][SP][0][1]);                    \
        q[T][SP][0][2] = fmaf(0.25f, s2_, q[T][SP][0][2]);                    \
        q[T][SP][1][0] += s0_; q[T][SP][1][1] += s1_; q[T][SP][1][2] += s2_;  \
        q[T][SP][2][0] = fmaf(0.25f, t0_, q[T][SP][2][0]);                    \
        q[T][SP][2][1] = fmaf(0.25f, t1_, q[T][SP][2][1]);                    \
        q[T][SP][2][2] = fmaf(0.25f, t2_, q[T][SP][2][2]);                    \
    }                                                                         \
} while (0)

// one tensor, one plane: batch the 3 row-loads (branchless), mask, then math
#define TENPASS(T, SP, PB) do {                                               \
    const float* r0_ = (PB) + po_ + ho0;                                      \
    const float* r1_ = (PB) + po_ + ho1;                                      \
    const float* r2_ = (PB) + po_ + ho2;                                      \
    float x00_ = r0_[0], x01_ = r0_[1], x02_ = r0_[2];                        \
    float x10_ = r1_[0], x11_ = r1_[1], x12_ = r1_[2];                        \
    float x20_ = r2_[0], x21_ = r2_[1], x22_ = r2_[2];                        \
    x00_ *= m0_; x01_ *= m0_; x02_ *= m0_;                                    \
    x10_ *= m1_; x11_ *= m1_; x12_ *= m1_;                                    \
    x20_ *= m2_; x21_ *= m2_; x22_ *= m2_;                                    \
    MATHROW(T, SP, 0, x00_, x01_, x02_);                                      \
    MATHROW(T, SP, 1, x10_, x11_, x12_);                                      \
    MATHROW(T, SP, 2, x20_, x21_, x22_);                                      \
} while (0)

#define PROCESS(SP, P) do {                                                   \
    const long long po_ =                                                     \
        (long long)((P) < 0 ? 0 : ((P) > ND - 1 ? ND - 1 : (P))) * PL;        \
    const float pm_ = ((P) >= 0 && (P) < ND) ? 1.f : 0.f;                     \
    const float m0_ = pm_ * hm0, m1_ = pm_, m2_ = pm_ * hm2;                  \
    TENPASS(0, SP, pb0);                                                      \
    TENPASS(1, SP, pb1);                                                      \
} while (0)

#define EDGE(T, J, SM, SC, SP, EVAR) do {                                     \
    const float gx_ = fmaf(2.f, q[T][SC][2][J], q[T][SM][2][J] + q[T][SP][2][J]) * 0.25f; \
    const float gy_ = fmaf(2.f, q[T][SC][1][J], q[T][SM][1][J] + q[T][SP][1][J]) * 0.25f; \
    const float gz_ = q[T][SP][0][J] - q[T][SM][0][J];                        \
    EVAR = sqrtf(fmaf(gx_, gx_, fmaf(gy_, gy_, fmaf(gz_, gz_, 1e-8f))));      \
} while (0)

#define EMIT(SM, SC, SP) do {                                                 \
    float e0_, e1_;                                                           \
    EDGE(0, 0, SM, SC, SP, e0_); EDGE(1, 0, SM, SC, SP, e1_); acc += fabsf(e0_ - e1_); \
    EDGE(0, 1, SM, SC, SP, e0_); EDGE(1, 1, SM, SC, SP, e1_); acc += fabsf(e0_ - e1_); \
    EDGE(0, 2, SM, SC, SP, e0_); EDGE(1, 2, SM, SC, SP, e1_); acc += fabsf(e0_ - e1_); \
} while (0)

    // prologue: planes d0-1 (slot 0), d0 (slot 1)
    PROCESS(0, d0 - 1);
    PROCESS(1, d0);

    // steady state: 5 groups x 3 phases; slot pattern (2,0,1)
    for (int g = 0; g < 5; ++g) {
        const int p = d0 + 1 + g * 3;
        PROCESS(2, p);     EMIT(0, 1, 2);
        PROCESS(0, p + 1); EMIT(1, 2, 0);
        PROCESS(1, p + 2); EMIT(2, 0, 1);
    }
    // epilogue: plane d0+16 (masked out for the last block), emit d0+15
    PROCESS(2, d0 + CD);
    EMIT(0, 1, 2);

#undef MATHROW
#undef TENPASS
#undef PROCESS
#undef EDGE
#undef EMIT

    // wave reduce -> block reduce -> one atomic per block
    #pragma unroll
    for (int off = 32; off > 0; off >>= 1)
        acc += __shfl_down(acc, off, 64);
    __shared__ float wsum[4];
    if (lane == 0) wsum[wid] = acc;
    __syncthreads();
    if (threadIdx.x == 0) {
        const float invN = 1.f / (float)((long long)NB * ND * NH * NW);
        atomicAdd(out, (wsum[0] + wsum[1] + wsum[2] + wsum[3]) * invN);
    }
}

} // namespace

extern "C" void kernel_launch(void* const* d_in, const int* in_sizes, int n_in,
                              void* d_out, int out_size, void* d_ws, size_t ws_size,
                              hipStream_t stream) {
    const float* pred = (const float*)d_in[0];
    const float* targ = (const float*)d_in[1];
    float* out = (float*)d_out;
    (void)in_sizes; (void)n_in; (void)out_size; (void)d_ws; (void)ws_size;

    hipMemsetAsync(out, 0, sizeof(float), stream);

    dim3 grid(ND / CD, NH / 4, NB);   // (8, 48, 4) = 1536 blocks, all co-resident
    dim3 block(256);
    edge_loss3d<<<grid, block, 0, stream>>>(pred, targ, out);
}

// Round 5
// 98.956 us; speedup vs baseline: 2.8127x; 2.8127x over previous
//
#include <hip/hip_runtime.h>

namespace {

constexpr int NB = 4;
constexpr int ND = 128;
constexpr int NH = 192;
constexpr int NW = 192;
constexpr int CD = 16;   // output planes per block; 128/16 = 8 exact

__global__ __launch_bounds__(256, 2)
void edge_loss3d(const float* __restrict__ pred,
                 const float* __restrict__ targ,
                 float* __restrict__ out)
{
    const int lane = threadIdx.x & 63;
    const int wid  = threadIdx.x >> 6;
    const int d0   = blockIdx.x * CD;
    const int h    = blockIdx.y * 4 + wid;   // output row, 0..191
    const int b    = blockIdx.z;
    const int w0   = lane * 3;               // 64 lanes x 3 w = 192, all active

    const long long base = (long long)b * ND * NH * NW;

    // rolling state: q[tensor][slot][kind 0=ss 1=ts 2=st][w]
    // EVERY index below is a textual literal -> guaranteed SROA to VGPRs.
    float q[2][3][3][3];
    float acc = 0.f;

// one h-row pass of one tensor into slot SP (T, SP, RR are literals)
#define ROWPASS(T, SP, RR, P) do {                                            \
    const float* __restrict__ src_ = (T) ? targ : pred;                       \
    const int hh_ = h - 1 + (RR);                                             \
    const bool hv_ = ((P) >= 0) && ((P) < ND) && (hh_ >= 0) && (hh_ < NH);    \
    float x0_ = 0.f, x1_ = 0.f, x2_ = 0.f;                                    \
    if (hv_) {                                                                \
        const float* rp_ = src_ + base + ((long long)(P) * NH + hh_) * NW + w0;\
        x0_ = rp_[0]; x1_ = rp_[1]; x2_ = rp_[2];                             \
    }                                                                         \
    float xl_ = __shfl_up(x2_, 1, 64);   if (lane == 0)  xl_ = 0.f;           \
    float xr_ = __shfl_down(x0_, 1, 64); if (lane == 63) xr_ = 0.f;           \
    const float s0_ = fmaf(2.f, x0_, xl_ + x1_) * 0.25f;                      \
    const float s1_ = fmaf(2.f, x1_, x0_ + x2_) * 0.25f;                      \
    const float s2_ = fmaf(2.f, x2_, x1_ + xr_) * 0.25f;                      \
    const float t0_ = x1_ - xl_, t1_ = x2_ - x0_, t2_ = xr_ - x1_;            \
    if ((RR) == 0) {                                                          \
        q[T][SP][0][0] = 0.25f*s0_; q[T][SP][0][1] = 0.25f*s1_; q[T][SP][0][2] = 0.25f*s2_; \
        q[T][SP][1][0] = -s0_;      q[T][SP][1][1] = -s1_;      q[T][SP][1][2] = -s2_;      \
        q[T][SP][2][0] = 0.25f*t0_; q[T][SP][2][1] = 0.25f*t1_; q[T][SP][2][2] = 0.25f*t2_; \
    } else if ((RR) == 1) {                                                   \
        q[T][SP][0][0] = fmaf(0.5f, s0_, q[T][SP][0][0]);                     \
        q[T][SP][0][1] = fmaf(0.5f, s1_, q[T][SP][0][1]);                     \
        q[T][SP][0][2] = fmaf(0.5f, s2_, q[T][SP][0][2]);                     \
        /* sobel_h center weight = 0 -> ts unchanged */                       \
        q[T][SP][2][0] = fmaf(0.5f, t0_, q[T][SP][2][0]);                     \
        q[T][SP][2][1] = fmaf(0.5f, t1_, q[T][SP][2][1]);                     \
        q[T][SP][2][2] = fmaf(0.5f, t2_, q[T][SP][2][2]);                     \
    } else {                                                                  \
        q[T][SP][0][0] = fmaf(0.25f, s0_, q[T][SP][0][0]);                    \
        q[T][SP][0][1] = fmaf(0.25f, s1_, q[T][SP][0][1]);                    \
        q[T][SP][0][2] = fmaf(0.25f, s2_, q[T][SP][0][2]);                    \
        q[T][SP][1][0] += s0_; q[T][SP][1][1] += s1_; q[T][SP][1][2] += s2_;  \
        q[T][SP][2][0] = fmaf(0.25f, t0_, q[T][SP][2][0]);                    \
        q[T][SP][2][1] = fmaf(0.25f, t1_, q[T][SP][2][1]);                    \
        q[T][SP][2][2] = fmaf(0.25f, t2_, q[T][SP][2][2]);                    \
    }                                                                         \
} while (0)

#define PROCESS(SP, P) do {                                                   \
    ROWPASS(0, SP, 0, P); ROWPASS(0, SP, 1, P); ROWPASS(0, SP, 2, P);         \
    ROWPASS(1, SP, 0, P); ROWPASS(1, SP, 1, P); ROWPASS(1, SP, 2, P);         \
} while (0)

#define EDGE(T, J, SM, SC, SP, EVAR) do {                                     \
    const float gx_ = fmaf(2.f, q[T][SC][2][J], q[T][SM][2][J] + q[T][SP][2][J]) * 0.25f; \
    const float gy_ = fmaf(2.f, q[T][SC][1][J], q[T][SM][1][J] + q[T][SP][1][J]) * 0.25f; \
    const float gz_ = q[T][SP][0][J] - q[T][SM][0][J];                        \
    EVAR = sqrtf(fmaf(gx_, gx_, fmaf(gy_, gy_, fmaf(gz_, gz_, 1e-8f))));      \
} while (0)

#define EMIT(SM, SC, SP) do {                                                 \
    float e0_, e1_;                                                           \
    EDGE(0, 0, SM, SC, SP, e0_); EDGE(1, 0, SM, SC, SP, e1_); acc += fabsf(e0_ - e1_); \
    EDGE(0, 1, SM, SC, SP, e0_); EDGE(1, 1, SM, SC, SP, e1_); acc += fabsf(e0_ - e1_); \
    EDGE(0, 2, SM, SC, SP, e0_); EDGE(1, 2, SM, SC, SP, e1_); acc += fabsf(e0_ - e1_); \
} while (0)

    // prologue: planes d0-1 (slot 0), d0 (slot 1)
    PROCESS(0, d0 - 1);
    PROCESS(1, d0);

    // steady state: 5 groups x 3 phases; slot pattern (2,0,1) repeats
    for (int g = 0; g < 5; ++g) {
        const int p = d0 + 1 + g * 3;
        PROCESS(2, p);     EMIT(0, 1, 2);
        PROCESS(0, p + 1); EMIT(1, 2, 0);
        PROCESS(1, p + 2); EMIT(2, 0, 1);
    }
    // epilogue: plane d0+16 (ROWPASS masks it out for the last block), emit d0+15
    PROCESS(2, d0 + CD);
    EMIT(0, 1, 2);

#undef ROWPASS
#undef PROCESS
#undef EDGE
#undef EMIT

    // wave reduce -> block reduce -> one atomic per block
    #pragma unroll
    for (int off = 32; off > 0; off >>= 1)
        acc += __shfl_down(acc, off, 64);
    __shared__ float wsum[4];
    if (lane == 0) wsum[wid] = acc;
    __syncthreads();
    if (threadIdx.x == 0) {
        const float invN = 1.f / (float)((long long)NB * ND * NH * NW);
        atomicAdd(out, (wsum[0] + wsum[1] + wsum[2] + wsum[3]) * invN);
    }
}

} // namespace

extern "C" void kernel_launch(void* const* d_in, const int* in_sizes, int n_in,
                              void* d_out, int out_size, void* d_ws, size_t ws_size,
                              hipStream_t stream) {
    const float* pred = (const float*)d_in[0];
    const float* targ = (const float*)d_in[1];
    float* out = (float*)d_out;
    (void)in_sizes; (void)n_in; (void)out_size; (void)d_ws; (void)ws_size;

    hipMemsetAsync(out, 0, sizeof(float), stream);

    dim3 grid(ND / CD, NH / 4, NB);   // (8, 48, 4) = 1536 blocks, single round
    dim3 block(256);
    edge_loss3d<<<grid, block, 0, stream>>>(pred, targ, out);
}

// Round 6
// 67.148 us; speedup vs baseline: 4.1451x; 1.4737x over previous
//
#include <hip/hip_runtime.h>

namespace {

constexpr int NB = 4;
constexpr int ND = 128;
constexpr int NH = 192;
constexpr int NW = 192;
constexpr int CD = 32;    // output planes per block; 128/32 = 4 exact
constexpr int LDSW = 194; // 1 left pad + 192 + 1 right pad

__global__ __launch_bounds__(256, 2)
void edge_loss3d(const float* __restrict__ pred,
                 const float* __restrict__ targ,
                 float* __restrict__ out)
{
    const int lane = threadIdx.x & 63;
    const int wid  = threadIdx.x >> 6;
    const int d0   = blockIdx.x * CD;
    const int h0   = blockIdx.y * 4;          // block's 4 output rows h0..h0+3
    const int b    = blockIdx.z;

    const long long PL = (long long)NH * NW;

    __shared__ float lds[2][6][LDSW];
    __shared__ float wsum[4];

    // zero the w-pads once (visible after the first PROCESS's barriers)
    if (threadIdx.x < 24) {
        const int t = threadIdx.x / 12, r = (threadIdx.x % 12) / 2, s = threadIdx.x & 1;
        lds[t][r][s * (LDSW - 1)] = 0.f;
    }

    // staging role: wave stages tensor tw, staged rows rbase..rbase+2 (rs=0 <-> h0-1)
    const int tw = wid >> 1;
    const int rbase = (wid & 1) * 3;
    const float* sb = (tw ? targ : pred) + (long long)b * ND * PL + 3 * lane;

    // per-staged-row offsets (clamped) and validity masks — constant over planes
    const int hh0 = h0 - 1 + rbase, hh1 = hh0 + 1, hh2 = hh0 + 2;
    const int ro0 = (hh0 < 0 ? 0 : (hh0 > NH - 1 ? NH - 1 : hh0)) * NW;
    const int ro1 = (hh1 < 0 ? 0 : (hh1 > NH - 1 ? NH - 1 : hh1)) * NW;
    const int ro2 = (hh2 < 0 ? 0 : (hh2 > NH - 1 ? NH - 1 : hh2)) * NW;
    const float rm0 = (hh0 >= 0 && hh0 < NH) ? 1.f : 0.f;
    const float rm1 = (hh1 >= 0 && hh1 < NH) ? 1.f : 0.f;
    const float rm2 = (hh2 >= 0 && hh2 < NH) ? 1.f : 0.f;

    float* ldw = &lds[tw][rbase][1 + 3 * lane];
    const float* ldr0 = &lds[0][wid][1 + 3 * lane];
    const float* ldr1 = &lds[1][wid][1 + 3 * lane];

    // in-flight staged rows (9 scalars) and rolling state q (literal indices only)
    float g00, g01, g02, g10, g11, g12, g20, g21, g22;
    float q[2][3][3][3];
    float acc = 0.f;

#define PREFETCH(P) do {                                                      \
    const int pc_ = (P) < 0 ? 0 : ((P) > ND - 1 ? ND - 1 : (P));              \
    const float* sp_ = sb + (long long)pc_ * PL;                              \
    const float pm_ = ((P) >= 0 && (P) < ND) ? 1.f : 0.f;                     \
    const float m0_ = pm_ * rm0, m1_ = pm_ * rm1, m2_ = pm_ * rm2;            \
    g00 = sp_[ro0 + 0] * m0_; g01 = sp_[ro0 + 1] * m0_; g02 = sp_[ro0 + 2] * m0_; \
    g10 = sp_[ro1 + 0] * m1_; g11 = sp_[ro1 + 1] * m1_; g12 = sp_[ro1 + 2] * m1_; \
    g20 = sp_[ro2 + 0] * m2_; g21 = sp_[ro2 + 1] * m2_; g22 = sp_[ro2 + 2] * m2_; \
} while (0)

#define STAGE_WRITE() do {                                                    \
    ldw[0] = g00; ldw[1] = g01; ldw[2] = g02;                                 \
    ldw[LDSW + 0] = g10; ldw[LDSW + 1] = g11; ldw[LDSW + 2] = g12;            \
    ldw[2 * LDSW + 0] = g20; ldw[2 * LDSW + 1] = g21; ldw[2 * LDSW + 2] = g22;\
} while (0)

// one h-row pass of tensor T into slot SP; reads staged row (wid+RR) from LDS
#define ROWPASS(T, SP, RR) do {                                               \
    const float* rp_ = (T ? ldr1 : ldr0) + (RR) * LDSW;                       \
    const float xm_ = rp_[-1], x0_ = rp_[0], x1_ = rp_[1], x2_ = rp_[2], xp_ = rp_[3]; \
    const float s0_ = fmaf(2.f, x0_, xm_ + x1_) * 0.25f;                      \
    const float s1_ = fmaf(2.f, x1_, x0_ + x2_) * 0.25f;                      \
    const float s2_ = fmaf(2.f, x2_, x1_ + xp_) * 0.25f;                      \
    const float t0_ = x1_ - xm_, t1_ = x2_ - x0_, t2_ = xp_ - x1_;            \
    if ((RR) == 0) {                                                          \
        q[T][SP][0][0] = 0.25f*s0_; q[T][SP][0][1] = 0.25f*s1_; q[T][SP][0][2] = 0.25f*s2_; \
        q[T][SP][1][0] = -s0_;      q[T][SP][1][1] = -s1_;      q[T][SP][1][2] = -s2_;      \
        q[T][SP][2][0] = 0.25f*t0_; q[T][SP][2][1] = 0.25f*t1_; q[T][SP][2][2] = 0.25f*t2_; \
    } else if ((RR) == 1) {                                                   \
        q[T][SP][0][0] = fmaf(0.5f, s0_, q[T][SP][0][0]);                     \
        q[T][SP][0][1] = fmaf(0.5f, s1_, q[T][SP][0][1]);                     \
        q[T][SP][0][2] = fmaf(0.5f, s2_, q[T][SP][0][2]);                     \
        /* sobel_h center weight = 0 -> ts unchanged */                       \
        q[T][SP][2][0] = fmaf(0.5f, t0_, q[T][SP][2][0]);                     \
        q[T][SP][2][1] = fmaf(0.5f, t1_, q[T][SP][2][1]);                     \
        q[T][SP][2][2] = fmaf(0.5f, t2_, q[T][SP][2][2]);                     \
    } else {                                                                  \
        q[T][SP][0][0] = fmaf(0.25f, s0_, q[T][SP][0][0]);                    \
        q[T][SP][0][1] = fmaf(0.25f, s1_, q[T][SP][0][1]);                    \
        q[T][SP][0][2] = fmaf(0.25f, s2_, q[T][SP][0][2]);                    \
        q[T][SP][1][0] += s0_; q[T][SP][1][1] += s1_; q[T][SP][1][2] += s2_;  \
        q[T][SP][2][0] = fmaf(0.25f, t0_, q[T][SP][2][0]);                    \
        q[T][SP][2][1] = fmaf(0.25f, t1_, q[T][SP][2][1]);                    \
        q[T][SP][2][2] = fmaf(0.25f, t2_, q[T][SP][2][2]);                    \
    }                                                                         \
} while (0)

// write staged plane to LDS, prefetch plane PNEXT, compute staged plane into slot SP
#define PROCESS(SP, PNEXT) do {                                               \
    __syncthreads();                                                          \
    STAGE_WRITE();                                                            \
    __syncthreads();                                                          \
    PREFETCH(PNEXT);                                                          \
    ROWPASS(0, SP, 0); ROWPASS(0, SP, 1); ROWPASS(0, SP, 2);                  \
    ROWPASS(1, SP, 0); ROWPASS(1, SP, 1); ROWPASS(1, SP, 2);                  \
} while (0)

#define PROCESS_LAST(SP) do {                                                 \
    __syncthreads();                                                          \
    STAGE_WRITE();                                                            \
    __syncthreads();                                                          \
    ROWPASS(0, SP, 0); ROWPASS(0, SP, 1); ROWPASS(0, SP, 2);                  \
    ROWPASS(1, SP, 0); ROWPASS(1, SP, 1); ROWPASS(1, SP, 2);                  \
} while (0)

#define EDGE(T, J, SM, SC, SP, EVAR) do {                                     \
    const float gx_ = fmaf(2.f, q[T][SC][2][J], q[T][SM][2][J] + q[T][SP][2][J]) * 0.25f; \
    const float gy_ = fmaf(2.f, q[T][SC][1][J], q[T][SM][1][J] + q[T][SP][1][J]) * 0.25f; \
    const float gz_ = q[T][SP][0][J] - q[T][SM][0][J];                        \
    EVAR = sqrtf(fmaf(gx_, gx_, fmaf(gy_, gy_, fmaf(gz_, gz_, 1e-8f))));      \
} while (0)

#define EMIT(SM, SC, SP) do {                                                 \
    float e0_, e1_;                                                           \
    EDGE(0, 0, SM, SC, SP, e0_); EDGE(1, 0, SM, SC, SP, e1_); acc += fabsf(e0_ - e1_); \
    EDGE(0, 1, SM, SC, SP, e0_); EDGE(1, 1, SM, SC, SP, e1_); acc += fabsf(e0_ - e1_); \
    EDGE(0, 2, SM, SC, SP, e0_); EDGE(1, 2, SM, SC, SP, e1_); acc += fabsf(e0_ - e1_); \
} while (0)

    // prologue: plane d0-1 -> slot 0, plane d0 -> slot 1
    PREFETCH(d0 - 1);
    PROCESS(0, d0);          // computes plane d0-1
    PROCESS(1, d0 + 1);      // computes plane d0

    // steady state: 10 groups x 3 phases; computed planes d0+1 .. d0+30
    for (int gg = 0; gg < 10; ++gg) {
        const int pn = d0 + 2 + gg * 3;      // prefetch args (computed plane + 1)
        PROCESS(2, pn);     EMIT(0, 1, 2);   // emit output plane d0+3*gg
        PROCESS(0, pn + 1); EMIT(1, 2, 0);
        PROCESS(1, pn + 2); EMIT(2, 0, 1);
    }
    // epilogue: compute d0+31, d0+32; emit outputs d0+30, d0+31
    PROCESS(2, d0 + 32); EMIT(0, 1, 2);
    PROCESS_LAST(0);     EMIT(1, 2, 0);

#undef PREFETCH
#undef STAGE_WRITE
#undef ROWPASS
#undef PROCESS
#undef PROCESS_LAST
#undef EDGE
#undef EMIT

    // wave reduce -> block reduce -> one atomic per block
    #pragma unroll
    for (int off = 32; off > 0; off >>= 1)
        acc += __shfl_down(acc, off, 64);
    if (lane == 0) wsum[wid] = acc;
    __syncthreads();
    if (threadIdx.x == 0) {
        const float invN = 1.f / (float)((long long)NB * ND * NH * NW);
        atomicAdd(out, (wsum[0] + wsum[1] + wsum[2] + wsum[3]) * invN);
    }
}

} // namespace

extern "C" void kernel_launch(void* const* d_in, const int* in_sizes, int n_in,
                              void* d_out, int out_size, void* d_ws, size_t ws_size,
                              hipStream_t stream) {
    const float* pred = (const float*)d_in[0];
    const float* targ = (const float*)d_in[1];
    float* out = (float*)d_out;
    (void)in_sizes; (void)n_in; (void)out_size; (void)d_ws; (void)ws_size;

    hipMemsetAsync(out, 0, sizeof(float), stream);

    dim3 grid(ND / CD, NH / 4, NB);   // (4, 48, 4) = 768 blocks, 3/CU, all resident
    dim3 block(256);
    edge_loss3d<<<grid, block, 0, stream>>>(pred, targ, out);
}